// Round 7
// baseline (112.519 us; speedup 1.0000x reference)
//
#include <hip/hip_runtime.h>
#include <math.h>

// Problem constants
#define BATCH 4
#define NNODE 10000
#define EDIM  32
#define CDIM  128
#define ODIM  128
#define MTOT  (BATCH * NNODE)   // 40000

typedef __attribute__((ext_vector_type(8))) short bf16x8;   // MFMA A/B frag (4 VGPRs)
typedef __attribute__((ext_vector_type(4))) float f32x4;    // MFMA C/D frag

// Sentinel bf16 pattern: -2^120. As an fp16 bit-interp it is -65504 (most
// negative finite fp16) -> always loses a v_pk_max_f16 against any real T
// value (|T|<16 -> patterns map to small finite fp16), and is NOT fp16-NaN,
// so max semantics are purely bitwise-monotone selection. See gather_max.
#define SENT_BF16 0xFBFFu

__device__ __forceinline__ unsigned short f2bf(float f) {
    unsigned u = __float_as_uint(f);
    u += 0x7fffu + ((u >> 16) & 1u);   // RTNE
    return (unsigned short)(u >> 16);
}
__device__ __forceinline__ float bf2f(unsigned short h) {
    return __uint_as_float(((unsigned)h) << 16);
}
__device__ __forceinline__ void pkmax(unsigned& acc, unsigned v) {
    // packed max of two bf16 bit-patterns via fp16 compare (monotone for
    // the occurring patterns; no NaNs by construction)
    asm("v_pk_max_f16 %0, %0, %1" : "+v"(acc) : "v"(v));
}

// ---------------------------------------------------------------------------
// prep_w: Bcat[n][k] bf16, n-major so GEMM W-fragments are contiguous 16B
// loads. n<128: W1[k][n]-W2[k][n]; n>=128: W2[k][n-128]. 64KB, L2-hot.
// Also fills sentinel T row (row 40000) with SENT_BF16.
// ---------------------------------------------------------------------------
__global__ __launch_bounds__(256) void prep_w(
    const float* __restrict__ W, unsigned short* __restrict__ Bcat,
    unsigned short* __restrict__ Tsent)
{
    int gid = blockIdx.x * 256 + threadIdx.x;   // 32768 threads
    int n = gid >> 7;          // 0..255
    int k = gid & 127;         // 0..127
    float v;
    if (n < 128) v = W[(size_t)k * ODIM + n] - W[(size_t)(k + 128) * ODIM + n];
    else         v = W[(size_t)(k + 128) * ODIM + (n - 128)];
    Bcat[(size_t)n * CDIM + k] = f2bf(v);
    if (gid < ODIM) Tsent[gid] = (unsigned short)SENT_BF16;
}

// ---------------------------------------------------------------------------
// MFMA GEMM, LDS-staged, OPERANDS SWAPPED so the epilogue is direct stores.
// A-operand = W-frag (m-index = output col), B-operand = x-frag (n-index =
// x row) => D: col(lane&15) = x row, row(quad*4+reg) = output col. Each
// lane's 4 regs per tile = 4 CONSECUTIVE output cols of ONE row -> one
// ushort4 store per tile, bias via broadcast float4. No epilogue LDS, no
// extra barriers (1 total).
// Block = 32 rows x 256 cols (cols 0..127 -> U bf16+bias, 128..255 -> T
// bf16), 1250 blocks (~4.9/CU), 4 waves x 64-col quarter, 2x4 tiles, K=128.
// A(x)-staging: coalesced float4, fp32->bf16, kblk-XOR-swizzled LDS (<=2-way).
// Fragment layouts (R4-R6 verified): frag[m-or-n=lane&15][k=quad*8+j].
// ---------------------------------------------------------------------------
__global__ __launch_bounds__(256) void gemm_mfma(
    const float* __restrict__ x,            // [40000,128]
    const unsigned short* __restrict__ Bcat,// [256,128] bf16
    const float* __restrict__ bias,         // [128]
    unsigned short* __restrict__ U,         // [40000,128] bf16
    unsigned short* __restrict__ T)         // [40001,128] bf16
{
    __shared__ unsigned short As[32 * 128]; // 8KB, swizzled [row][k]

    const int tid  = threadIdx.x;
    const int m0   = blockIdx.x * 32;
    const int wv   = tid >> 6;
    const int lane = tid & 63;
    const int l16  = lane & 15;
    const int quad = lane >> 4;
    const int nq   = wv * 64;

    // ---- stage + convert: 32 rows x 128 k, coalesced float4 reads ----
    #pragma unroll
    for (int i = 0; i < 4; i++) {
        int lin = i * 256 + tid;            // float4 index, 0..1023
        int row = lin >> 5;                 // 0..31
        int f4  = lin & 31;                 // float4 within row
        float4 v = *(const float4*)&x[(size_t)(m0 + row) * CDIM + f4 * 4];
        ushort4 h;
        h.x = f2bf(v.x); h.y = f2bf(v.y); h.z = f2bf(v.z); h.w = f2bf(v.w);
        int kblk = f4 >> 1, half = f4 & 1;
        *(ushort4*)((char*)As + row * 256 + (((kblk ^ (row & 15)) << 4) + half * 8)) = h;
    }
    __syncthreads();

    f32x4 acc[2][4];
    #pragma unroll
    for (int i = 0; i < 2; i++)
        #pragma unroll
        for (int j = 0; j < 4; j++) acc[i][j] = (f32x4){0.f, 0.f, 0.f, 0.f};

    #pragma unroll
    for (int ks = 0; ks < 4; ks++) {
        const int kb = ks * 32 + quad * 8;

        bf16x8 wfr[4];                      // A-operand: W cols nq+ct*16+l16
        #pragma unroll
        for (int ct = 0; ct < 4; ct++)
            wfr[ct] = *(const bf16x8*)(Bcat + (size_t)(nq + ct * 16 + l16) * CDIM + kb);

        bf16x8 xfr[2];                      // B-operand: x rows rt*16+l16 (LDS)
        #pragma unroll
        for (int rt = 0; rt < 2; rt++) {
            int row  = rt * 16 + l16;
            int kblk = ks * 4 + quad;
            xfr[rt] = *(const bf16x8*)((char*)As + row * 256 + ((kblk ^ l16) << 4));
        }

        #pragma unroll
        for (int rt = 0; rt < 2; rt++)
            #pragma unroll
            for (int ct = 0; ct < 4; ct++)
                acc[rt][ct] = __builtin_amdgcn_mfma_f32_16x16x32_bf16(
                    wfr[ct], xfr[rt], acc[rt][ct], 0, 0, 0);
    }

    // ---- epilogue: direct packed stores, no LDS ----
    if (wv < 2) {                           // U cols 0..127 (+bias)
        #pragma unroll
        for (int ct = 0; ct < 4; ct++) {
            int c0 = nq + ct * 16 + quad * 4;
            float4 b4 = *(const float4*)&bias[c0];   // broadcast across l16
            #pragma unroll
            for (int rt = 0; rt < 2; rt++) {
                int row = m0 + rt * 16 + l16;
                ushort4 h;
                h.x = f2bf(acc[rt][ct][0] + b4.x);
                h.y = f2bf(acc[rt][ct][1] + b4.y);
                h.z = f2bf(acc[rt][ct][2] + b4.z);
                h.w = f2bf(acc[rt][ct][3] + b4.w);
                *(ushort4*)&U[(size_t)row * ODIM + c0] = h;
            }
        }
    } else {                                // T cols 0..127
        #pragma unroll
        for (int ct = 0; ct < 4; ct++) {
            int c0 = (nq - 128) + ct * 16 + quad * 4;
            #pragma unroll
            for (int rt = 0; rt < 2; rt++) {
                int row = m0 + rt * 16 + l16;
                ushort4 h;
                h.x = f2bf(acc[rt][ct][0]);
                h.y = f2bf(acc[rt][ct][1]);
                h.z = f2bf(acc[rt][ct][2]);
                h.w = f2bf(acc[rt][ct][3]);
                *(ushort4*)&T[(size_t)row * ODIM + c0] = h;
            }
        }
    }
}

// ---------------------------------------------------------------------------
// Gather + max + elu. Quarter-wave (16 lanes) per node, uint4 = bf16x8 per
// lane -> one 1KB load instr per edge row. Invalid indices rewritten at
// staging to the SENT_BF16 sentinel row. Inner loop: 4 v_pk_max_f16 per
// uint4 (bf16 patterns are fp16-monotone in our range; sentinel always
// loses, no NaNs) -> 4 VALU/edge instead of 16. 16 loads in flight.
// "any valid" = low half of m01 != SENT (real T can't hit -2^120).
// XCD swizzle b=g&3: each XCD touches one batch's 2.56MB T slice (< 4MB L2).
// ---------------------------------------------------------------------------
__global__ __launch_bounds__(256) void gather_max(
    const int* __restrict__ idx,            // [40000,32]
    const unsigned short* __restrict__ Ub,  // [40000,128] bf16 (ws)
    const unsigned short* __restrict__ T,   // [40001,128] bf16 (ws)
    float* __restrict__ out)                // [40000,128] (d_out)
{
    __shared__ int sidx[16][EDIM];

    const int g   = blockIdx.x;             // 0..2499
    const int b   = g & 3;                  // batch
    const int nb0 = (g >> 2) * 16;          // first node (0..9984)
    const int tid = threadIdx.x;
    const int sent = NNODE * (BATCH - b);   // sentinel row rel. to tb

    #pragma unroll
    for (int i = 0; i < 2; i++) {
        int lin = i * 256 + tid;            // 0..511
        int n = lin >> 5, e = lin & 31;
        int j = idx[(size_t)(b * NNODE + nb0 + n) * EDIM + e];
        sidx[n][e] = (j < 0) ? sent : j;
    }
    __syncthreads();

    const int wv   = tid >> 6;
    const int lane = tid & 63;
    const int q4   = lane >> 4;
    const int l16  = lane & 15;
    const int myn  = wv * 4 + q4;           // 0..15
    const int node = b * NNODE + nb0 + myn;
    const unsigned short* tb = T + (size_t)b * NNODE * ODIM;
    const int o8 = l16 * 8;                 // bf16 col offset (16B aligned)

    uint4 uraw = *(const uint4*)(Ub + (size_t)node * ODIM + o8);  // prefetch U

    const unsigned SENT2 = (SENT_BF16 << 16) | SENT_BF16;
    unsigned m01 = SENT2, m23 = SENT2, m45 = SENT2, m67 = SENT2;

    #pragma unroll
    for (int e0 = 0; e0 < EDIM; e0 += 16) {
        uint4 v[16];
        #pragma unroll
        for (int q = 0; q < 16; q++) {      // 16 gathers in flight
            int j = sidx[myn][e0 + q];
            v[q] = *(const uint4*)(tb + (size_t)j * ODIM + o8);
        }
        #pragma unroll
        for (int q = 0; q < 16; q++) {
            pkmax(m01, v[q].x);
            pkmax(m23, v[q].y);
            pkmax(m45, v[q].z);
            pkmax(m67, v[q].w);
        }
    }

    const bool any = (m01 & 0xffffu) != SENT_BF16;
    float m[8];
    m[0] = bf2f((unsigned short)(m01 & 0xffff)); m[1] = bf2f((unsigned short)(m01 >> 16));
    m[2] = bf2f((unsigned short)(m23 & 0xffff)); m[3] = bf2f((unsigned short)(m23 >> 16));
    m[4] = bf2f((unsigned short)(m45 & 0xffff)); m[5] = bf2f((unsigned short)(m45 >> 16));
    m[6] = bf2f((unsigned short)(m67 & 0xffff)); m[7] = bf2f((unsigned short)(m67 >> 16));
    float uu[8];
    uu[0] = bf2f((unsigned short)(uraw.x & 0xffff)); uu[1] = bf2f((unsigned short)(uraw.x >> 16));
    uu[2] = bf2f((unsigned short)(uraw.y & 0xffff)); uu[3] = bf2f((unsigned short)(uraw.y >> 16));
    uu[4] = bf2f((unsigned short)(uraw.z & 0xffff)); uu[5] = bf2f((unsigned short)(uraw.z >> 16));
    uu[6] = bf2f((unsigned short)(uraw.w & 0xffff)); uu[7] = bf2f((unsigned short)(uraw.w >> 16));
    float r[8];
    #pragma unroll
    for (int i = 0; i < 8; i++) {
        float s = uu[i] + m[i];
        r[i] = any ? (s > 0.f ? s : __expf(s) - 1.f) : -INFINITY;
    }
    *(float4*)&out[(size_t)node * ODIM + o8]     = make_float4(r[0], r[1], r[2], r[3]);
    *(float4*)&out[(size_t)node * ODIM + o8 + 4] = make_float4(r[4], r[5], r[6], r[7]);
}

extern "C" void kernel_launch(void* const* d_in, const int* in_sizes, int n_in,
                              void* d_out, int out_size, void* d_ws, size_t ws_size,
                              hipStream_t stream) {
    const float* x    = (const float*)d_in[0];
    const int*   idx  = (const int*)d_in[1];
    const float* W    = (const float*)d_in[2];
    const float* bias = (const float*)d_in[3];
    float* out        = (float*)d_out;

    // ws layout: T bf16 [(40000+1)*128] | U bf16 [40000*128] | Bcat bf16 [256*128]
    const size_t tBytes = (size_t)(MTOT + 1) * ODIM * sizeof(unsigned short);
    const size_t uBytes = (size_t)MTOT * ODIM * sizeof(unsigned short);
    unsigned short* T    = (unsigned short*)d_ws;
    unsigned short* U    = (unsigned short*)((char*)d_ws + tBytes);
    unsigned short* Bcat = (unsigned short*)((char*)d_ws + tBytes + uBytes);
    unsigned short* Tsent = T + (size_t)MTOT * ODIM;

    prep_w    <<<128,        256, 0, stream>>>(W, Bcat, Tsent);
    gemm_mfma <<<MTOT / 32,  256, 0, stream>>>(x, Bcat, bias, U, T);
    gather_max<<<MTOT / 16,  256, 0, stream>>>(idx, U, T, out);
}